// Round 1
// baseline (2497.426 us; speedup 1.0000x reference)
//
#include <hip/hip_runtime.h>
#include <hip/hip_bf16.h>

// Problem constants
#define NN 50000
#define DIN 256
#define KK 8
// global MLP dims: 256 -> 256 -> 128 -> 64 ; decoder 64 -> 24
// point MLP: 323 -> 256 -> 256 -> 256

#define TM1 8   // nodes per block, kernel 1  (50000 / 8 = 6250)
#define TM2 4   // nodes per block, kernel 2  (50000 / 4 = 12500) -> 32 point-rows

// ---------------------------------------------------------------------------
// Kernel 1: global feature MLP + decoder head + cluster write
// ---------------------------------------------------------------------------
__global__ __launch_bounds__(256) void k_global(
    const float* __restrict__ x,
    const float* __restrict__ Wg0, const float* __restrict__ bg0,
    const float* __restrict__ Wg1, const float* __restrict__ bg1,
    const float* __restrict__ Wg2, const float* __restrict__ bg2,
    const float* __restrict__ Wdec, const float* __restrict__ bdec,
    float* __restrict__ feats_ws,
    float* __restrict__ out_rel,
    float* __restrict__ out_cluster)
{
    __shared__ __attribute__((aligned(16))) float xin[TM1 * 256]; // 8 KB
    __shared__ __attribute__((aligned(16))) float h0[TM1 * 256];  // 8 KB
    __shared__ __attribute__((aligned(16))) float g1[TM1 * 128];  // 4 KB
    __shared__ __attribute__((aligned(16))) float g2[TM1 * 64];   // 2 KB

    const int tid = threadIdx.x;
    const int blk = blockIdx.x;

    // ---- load 8 contiguous node rows: 2048 floats = 512 float4
    {
        const float4* xg = (const float4*)(x + (size_t)blk * TM1 * 256);
        float4* xl = (float4*)xin;
        xl[tid]        = xg[tid];
        xl[tid + 256]  = xg[tid + 256];
    }
    __syncthreads();

    // ---- layer 0: 256 -> 256, thread j = column, 8 rows each
    {
        const int j = tid;
        float acc[TM1];
        float b = bg0[j];
        #pragma unroll
        for (int m = 0; m < TM1; ++m) acc[m] = b;
        for (int i = 0; i < 256; i += 4) {
            float w0 = Wg0[(size_t)(i + 0) * 256 + j];
            float w1 = Wg0[(size_t)(i + 1) * 256 + j];
            float w2 = Wg0[(size_t)(i + 2) * 256 + j];
            float w3 = Wg0[(size_t)(i + 3) * 256 + j];
            #pragma unroll
            for (int m = 0; m < TM1; ++m) {
                float4 xv = *(const float4*)&xin[m * 256 + i];
                acc[m] += xv.x * w0 + xv.y * w1 + xv.z * w2 + xv.w * w3;
            }
        }
        #pragma unroll
        for (int m = 0; m < TM1; ++m) h0[m * 256 + j] = fmaxf(acc[m], 0.f);
    }
    __syncthreads();

    // ---- layer 1: 256 -> 128; col = tid&127, row group tid>>7 (4 rows)
    {
        const int col = tid & 127;
        const int rg  = tid >> 7;   // 0..1
        float acc[4];
        float b = bg1[col];
        #pragma unroll
        for (int m = 0; m < 4; ++m) acc[m] = b;
        for (int i = 0; i < 256; i += 4) {
            float w0 = Wg1[(size_t)(i + 0) * 128 + col];
            float w1 = Wg1[(size_t)(i + 1) * 128 + col];
            float w2 = Wg1[(size_t)(i + 2) * 128 + col];
            float w3 = Wg1[(size_t)(i + 3) * 128 + col];
            #pragma unroll
            for (int m = 0; m < 4; ++m) {
                int r = rg * 4 + m;
                float4 xv = *(const float4*)&h0[r * 256 + i];
                acc[m] += xv.x * w0 + xv.y * w1 + xv.z * w2 + xv.w * w3;
            }
        }
        #pragma unroll
        for (int m = 0; m < 4; ++m) g1[(rg * 4 + m) * 128 + col] = fmaxf(acc[m], 0.f);
    }
    __syncthreads();

    // ---- layer 2: 128 -> 64; col = tid&63, row group tid>>6 (2 rows)
    {
        const int col = tid & 63;
        const int rg  = tid >> 6;   // 0..3
        float acc[2];
        float b = bg2[col];
        acc[0] = b; acc[1] = b;
        for (int i = 0; i < 128; i += 4) {
            float w0 = Wg2[(size_t)(i + 0) * 64 + col];
            float w1 = Wg2[(size_t)(i + 1) * 64 + col];
            float w2 = Wg2[(size_t)(i + 2) * 64 + col];
            float w3 = Wg2[(size_t)(i + 3) * 64 + col];
            #pragma unroll
            for (int m = 0; m < 2; ++m) {
                int r = rg * 2 + m;
                float4 xv = *(const float4*)&g1[r * 128 + i];
                acc[m] += xv.x * w0 + xv.y * w1 + xv.z * w2 + xv.w * w3;
            }
        }
        #pragma unroll
        for (int m = 0; m < 2; ++m) g2[(rg * 2 + m) * 64 + col] = fmaxf(acc[m], 0.f);
    }
    __syncthreads();

    // ---- write feats to workspace: 512 floats = 128 float4
    if (tid < 128) {
        float4* fw = (float4*)(feats_ws + (size_t)blk * TM1 * 64);
        fw[tid] = ((const float4*)g2)[tid];
    }

    // ---- decoder head: 8 nodes x 24 outputs, no relu -> rel points
    if (tid < 192) {
        int m = tid / 24;
        int c = tid - m * 24;
        float acc = bdec[c];
        for (int i = 0; i < 64; ++i) acc += g2[m * 64 + i] * Wdec[i * 24 + c];
        out_rel[(size_t)blk * 192 + tid] = acc;
    }

    // ---- cluster ids (as float): 64 point-rows per block
    if (tid < 64) {
        out_cluster[(size_t)blk * 64 + tid] = (float)(blk * TM1 + (tid >> 3));
    }
}

// ---------------------------------------------------------------------------
// Kernel 2: per-point MLP, fused concat via factorization
// ---------------------------------------------------------------------------
template <bool TO_GLOBAL>
__device__ __forceinline__ void fc_layer_32x256(
    const float* __restrict__ hsrc,   // LDS [32][256]
    const float* __restrict__ W,      // [256][256]
    const float* __restrict__ bias,   // [256]
    float* __restrict__ dst,          // LDS [32][256] or global base (block row 0)
    int tid)
{
    const int cg = tid & 63;   // columns 4cg .. 4cg+3
    const int rg = tid >> 6;   // rows 8rg .. 8rg+7 (wave-uniform)
    float4 bv = ((const float4*)bias)[cg];
    float acc[8][4];
    #pragma unroll
    for (int r = 0; r < 8; ++r) {
        acc[r][0] = bv.x; acc[r][1] = bv.y; acc[r][2] = bv.z; acc[r][3] = bv.w;
    }
    #pragma unroll 2
    for (int i = 0; i < 256; i += 2) {
        float4 w0 = ((const float4*)(W + (size_t)(i + 0) * 256))[cg];
        float4 w1 = ((const float4*)(W + (size_t)(i + 1) * 256))[cg];
        #pragma unroll
        for (int r = 0; r < 8; ++r) {
            float2 a = *(const float2*)&hsrc[(rg * 8 + r) * 256 + i];
            acc[r][0] += a.x * w0.x + a.y * w1.x;
            acc[r][1] += a.x * w0.y + a.y * w1.y;
            acc[r][2] += a.x * w0.z + a.y * w1.z;
            acc[r][3] += a.x * w0.w + a.y * w1.w;
        }
    }
    #pragma unroll
    for (int r = 0; r < 8; ++r) {
        float4 v;
        v.x = fmaxf(acc[r][0], 0.f);
        v.y = fmaxf(acc[r][1], 0.f);
        v.z = fmaxf(acc[r][2], 0.f);
        v.w = fmaxf(acc[r][3], 0.f);
        if (TO_GLOBAL) {
            ((float4*)(dst + (size_t)(rg * 8 + r) * 256))[cg] = v;
        } else {
            ((float4*)(dst + (rg * 8 + r) * 256))[cg] = v;
        }
    }
}

__global__ __launch_bounds__(256) void k_points(
    const float* __restrict__ x,
    const float* __restrict__ feats_ws,
    const float* __restrict__ rel_in,
    const float* __restrict__ W0, const float* __restrict__ b0,
    const float* __restrict__ W1, const float* __restrict__ b1,
    const float* __restrict__ W2, const float* __restrict__ b2,
    float* __restrict__ out_dec)
{
    __shared__ __attribute__((aligned(16))) float xin[TM2 * 256];  // 4 KB
    __shared__ __attribute__((aligned(16))) float fe[TM2 * 64];    // 1 KB
    __shared__ __attribute__((aligned(16))) float rl[TM2 * 24];    // 384 B
    __shared__ __attribute__((aligned(16))) float sbuf[TM2 * 256]; // 4 KB
    __shared__ __attribute__((aligned(16))) float h0[32 * 256];    // 32 KB
    __shared__ __attribute__((aligned(16))) float h1[32 * 256];    // 32 KB

    const int tid = threadIdx.x;
    const int blk = blockIdx.x;
    const size_t nb = (size_t)blk * TM2;   // first node of this block

    // ---- stage inputs
    {
        const float4* xg = (const float4*)(x + nb * 256);
        ((float4*)xin)[tid] = xg[tid];                 // 1024 floats = 256 f4
    }
    if (tid < 64)  ((float4*)fe)[tid] = ((const float4*)(feats_ws + nb * 64))[tid];
    if (tid < 96)  rl[tid] = rel_in[nb * 24 + tid];
    __syncthreads();

    // ---- shared pre-activation s[m][j] = inp@W0a + feats@W0b + b0 (no relu yet)
    {
        const int j = tid;
        float acc[TM2];
        float b = b0[j];
        #pragma unroll
        for (int m = 0; m < TM2; ++m) acc[m] = b;
        for (int i = 0; i < 256; i += 4) {
            float w0 = W0[(size_t)(i + 0) * 256 + j];
            float w1 = W0[(size_t)(i + 1) * 256 + j];
            float w2 = W0[(size_t)(i + 2) * 256 + j];
            float w3 = W0[(size_t)(i + 3) * 256 + j];
            #pragma unroll
            for (int m = 0; m < TM2; ++m) {
                float4 xv = *(const float4*)&xin[m * 256 + i];
                acc[m] += xv.x * w0 + xv.y * w1 + xv.z * w2 + xv.w * w3;
            }
        }
        for (int i = 0; i < 64; i += 4) {
            float w0 = W0[(size_t)(256 + i + 0) * 256 + j];
            float w1 = W0[(size_t)(256 + i + 1) * 256 + j];
            float w2 = W0[(size_t)(256 + i + 2) * 256 + j];
            float w3 = W0[(size_t)(256 + i + 3) * 256 + j];
            #pragma unroll
            for (int m = 0; m < TM2; ++m) {
                float4 fv = *(const float4*)&fe[m * 64 + i];
                acc[m] += fv.x * w0 + fv.y * w1 + fv.z * w2 + fv.w * w3;
            }
        }
        #pragma unroll
        for (int m = 0; m < TM2; ++m) sbuf[m * 256 + j] = acc[m];
    }
    __syncthreads();

    // ---- expand to h0[32][256] with rel-point correction, then relu
    {
        const int j = tid;
        float wa = W0[(size_t)320 * 256 + j];
        float wb = W0[(size_t)321 * 256 + j];
        float wc = W0[(size_t)322 * 256 + j];
        #pragma unroll
        for (int m = 0; m < TM2; ++m) {
            float sv = sbuf[m * 256 + j];
            #pragma unroll
            for (int p = 0; p < 8; ++p) {
                float ra = rl[m * 24 + p * 3 + 0];
                float rb = rl[m * 24 + p * 3 + 1];
                float rc = rl[m * 24 + p * 3 + 2];
                float v = sv + ra * wa + rb * wb + rc * wc;
                h0[(m * 8 + p) * 256 + j] = fmaxf(v, 0.f);
            }
        }
    }
    __syncthreads();

    // ---- FC layer 1: h1 = relu(h0 @ W1 + b1)
    fc_layer_32x256<false>(h0, W1, b1, h1, tid);
    __syncthreads();

    // ---- FC layer 2: out = relu(h1 @ W2 + b2) -> global
    fc_layer_32x256<true>(h1, W2, b2, out_dec + (size_t)blk * 32 * 256, tid);
}

// ---------------------------------------------------------------------------
extern "C" void kernel_launch(void* const* d_in, const int* in_sizes, int n_in,
                              void* d_out, int out_size, void* d_ws, size_t ws_size,
                              hipStream_t stream) {
    const float* x    = (const float*)d_in[0];
    const float* Wg0  = (const float*)d_in[1];
    const float* bg0  = (const float*)d_in[2];
    const float* Wg1  = (const float*)d_in[3];
    const float* bg1  = (const float*)d_in[4];
    const float* Wg2  = (const float*)d_in[5];
    const float* bg2  = (const float*)d_in[6];
    const float* Wdec = (const float*)d_in[7];
    const float* bdec = (const float*)d_in[8];
    const float* W0   = (const float*)d_in[9];
    const float* b0   = (const float*)d_in[10];
    const float* W1   = (const float*)d_in[11];
    const float* b1   = (const float*)d_in[12];
    const float* W2   = (const float*)d_in[13];
    const float* b2   = (const float*)d_in[14];

    float* out      = (float*)d_out;
    float* out_rel  = out;                         // [400000, 3]
    float* out_dec  = out + 1200000;               // [400000, 256]
    float* out_clu  = out + 103600000;             // [400000] as float
    float* feats_ws = (float*)d_ws;                // [50000, 64]

    k_global<<<NN / TM1, 256, 0, stream>>>(x, Wg0, bg0, Wg1, bg1, Wg2, bg2,
                                           Wdec, bdec, feats_ws, out_rel, out_clu);
    k_points<<<NN / TM2, 256, 0, stream>>>(x, feats_ws, out_rel,
                                           W0, b0, W1, b1, W2, b2, out_dec);
}

// Round 2
// 1057.824 us; speedup vs baseline: 2.3609x; 2.3609x over previous
//
#include <hip/hip_runtime.h>
#include <hip/hip_bf16.h>

typedef __attribute__((ext_vector_type(8))) __bf16 bf16x8;
typedef __attribute__((ext_vector_type(4))) float f32x4;

#define NN 50000
#define TM1 16    // nodes per block, kernel 1  (50000/16 = 3125)
#define NODES2 8  // nodes per block, kernel 2 -> 64 point rows (50000/8 = 6250)

// ws layout (bytes):
//   0        : W0t bf16 [256 n][320 k]   (81920 elts, 163840 B)
//   163840   : W1t bf16 [256 n][256 k]   (65536 elts, 131072 B)
//   294912   : W2t bf16 [256 n][256 k]   (65536 elts, 131072 B)
//   425984   : feats f32 [50000][64]     (12.8 MB)

__device__ __forceinline__ unsigned short f2bf(float f) {
    unsigned int u = __builtin_bit_cast(unsigned int, f);
    u = (u + 0x7FFFu + ((u >> 16) & 1u)) >> 16;   // RNE; inputs are finite
    return (unsigned short)u;
}

// ---------------------------------------------------------------------------
// Prep: convert + transpose point-MLP weights to bf16 in ws
// ---------------------------------------------------------------------------
__global__ __launch_bounds__(256) void k_prep(
    const float* __restrict__ W0, const float* __restrict__ W1,
    const float* __restrict__ W2, unsigned short* __restrict__ wbf)
{
    int idx = blockIdx.x * 256 + threadIdx.x;
    if (idx < 81920) {                       // W0t[n][k] = W0[k][n], k<320
        int n = idx / 320, k = idx - n * 320;
        wbf[idx] = f2bf(W0[(size_t)k * 256 + n]);
    } else if (idx < 147456) {               // W1t
        int e = idx - 81920;
        int n = e >> 8, k = e & 255;
        wbf[idx] = f2bf(W1[(size_t)k * 256 + n]);
    } else if (idx < 212992) {               // W2t
        int e = idx - 147456;
        int n = e >> 8, k = e & 255;
        wbf[idx] = f2bf(W2[(size_t)k * 256 + n]);
    }
}

// ---------------------------------------------------------------------------
// Kernel 1: global feature MLP + decoder head + cluster write (fp32)
// ---------------------------------------------------------------------------
__global__ __launch_bounds__(256) void k_global(
    const float* __restrict__ x,
    const float* __restrict__ Wg0, const float* __restrict__ bg0,
    const float* __restrict__ Wg1, const float* __restrict__ bg1,
    const float* __restrict__ Wg2, const float* __restrict__ bg2,
    const float* __restrict__ Wdec, const float* __restrict__ bdec,
    float* __restrict__ feats_ws,
    float* __restrict__ out_rel,
    float* __restrict__ out_cluster)
{
    __shared__ __attribute__((aligned(16))) float xin[TM1 * 256]; // 16 KB
    __shared__ __attribute__((aligned(16))) float h0[TM1 * 256];  // 16 KB
    __shared__ __attribute__((aligned(16))) float g1[TM1 * 128];  // 8 KB
    __shared__ __attribute__((aligned(16))) float g2[TM1 * 64];   // 4 KB

    const int tid = threadIdx.x;
    const int blk = blockIdx.x;

    // ---- load 16 node rows: 4096 floats = 1024 float4
    {
        const float4* xg = (const float4*)(x + (size_t)blk * TM1 * 256);
        float4* xl = (float4*)xin;
        #pragma unroll
        for (int it = 0; it < 4; ++it) xl[tid + it * 256] = xg[tid + it * 256];
    }
    __syncthreads();

    // ---- layer 0: 256 -> 256, thread j = column, 16 rows each
    {
        const int j = tid;
        float acc[TM1];
        float b = bg0[j];
        #pragma unroll
        for (int m = 0; m < TM1; ++m) acc[m] = b;
        for (int i = 0; i < 256; i += 4) {
            float w0 = Wg0[(size_t)(i + 0) * 256 + j];
            float w1 = Wg0[(size_t)(i + 1) * 256 + j];
            float w2 = Wg0[(size_t)(i + 2) * 256 + j];
            float w3 = Wg0[(size_t)(i + 3) * 256 + j];
            #pragma unroll
            for (int m = 0; m < TM1; ++m) {
                float4 xv = *(const float4*)&xin[m * 256 + i];
                acc[m] += xv.x * w0 + xv.y * w1 + xv.z * w2 + xv.w * w3;
            }
        }
        #pragma unroll
        for (int m = 0; m < TM1; ++m) h0[m * 256 + j] = fmaxf(acc[m], 0.f);
    }
    __syncthreads();

    // ---- layer 1: 256 -> 128; col = tid&127, 8 rows each
    {
        const int col = tid & 127;
        const int rg  = tid >> 7;   // 0..1
        float acc[8];
        float b = bg1[col];
        #pragma unroll
        for (int m = 0; m < 8; ++m) acc[m] = b;
        for (int i = 0; i < 256; i += 4) {
            float w0 = Wg1[(size_t)(i + 0) * 128 + col];
            float w1 = Wg1[(size_t)(i + 1) * 128 + col];
            float w2 = Wg1[(size_t)(i + 2) * 128 + col];
            float w3 = Wg1[(size_t)(i + 3) * 128 + col];
            #pragma unroll
            for (int m = 0; m < 8; ++m) {
                int r = rg * 8 + m;
                float4 xv = *(const float4*)&h0[r * 256 + i];
                acc[m] += xv.x * w0 + xv.y * w1 + xv.z * w2 + xv.w * w3;
            }
        }
        #pragma unroll
        for (int m = 0; m < 8; ++m) g1[(rg * 8 + m) * 128 + col] = fmaxf(acc[m], 0.f);
    }
    __syncthreads();

    // ---- layer 2: 128 -> 64; col = tid&63, 4 rows each
    {
        const int col = tid & 63;
        const int rg  = tid >> 6;   // 0..3
        float acc[4];
        float b = bg2[col];
        #pragma unroll
        for (int m = 0; m < 4; ++m) acc[m] = b;
        for (int i = 0; i < 128; i += 4) {
            float w0 = Wg2[(size_t)(i + 0) * 64 + col];
            float w1 = Wg2[(size_t)(i + 1) * 64 + col];
            float w2 = Wg2[(size_t)(i + 2) * 64 + col];
            float w3 = Wg2[(size_t)(i + 3) * 64 + col];
            #pragma unroll
            for (int m = 0; m < 4; ++m) {
                int r = rg * 4 + m;
                float4 xv = *(const float4*)&g1[r * 128 + i];
                acc[m] += xv.x * w0 + xv.y * w1 + xv.z * w2 + xv.w * w3;
            }
        }
        #pragma unroll
        for (int m = 0; m < 4; ++m) g2[(rg * 4 + m) * 64 + col] = fmaxf(acc[m], 0.f);
    }
    __syncthreads();

    // ---- write feats: 1024 floats = 256 float4
    {
        float4* fw = (float4*)(feats_ws + (size_t)blk * TM1 * 64);
        fw[tid] = ((const float4*)g2)[tid];
    }

    // ---- decoder head: 16 nodes x 24 outputs -> rel points
    for (int tt = tid; tt < TM1 * 24; tt += 256) {
        int m = tt / 24;
        int c = tt - m * 24;
        float acc = bdec[c];
        for (int i = 0; i < 64; ++i) acc += g2[m * 64 + i] * Wdec[i * 24 + c];
        out_rel[(size_t)blk * (TM1 * 24) + tt] = acc;
    }

    // ---- cluster ids (as float): 128 point rows per block
    if (tid < TM1 * 8) {
        out_cluster[(size_t)blk * (TM1 * 8) + tid] = (float)(blk * TM1 + (tid >> 3));
    }
}

// ---------------------------------------------------------------------------
// Kernel 2: per-point MLP via bf16 MFMA, fused concat via rank-3 factorization
// ---------------------------------------------------------------------------
__global__ __launch_bounds__(256) void k_points(
    const float* __restrict__ x,
    const float* __restrict__ feats_ws,
    const float* __restrict__ rel_in,
    const unsigned short* __restrict__ wbf,
    const float* __restrict__ W0f,       // fp32 W0, rows 320..322 (rel cols)
    const float* __restrict__ b0,
    const float* __restrict__ b1,
    const float* __restrict__ b2,
    float* __restrict__ out_dec)
{
    // LDS: h0 64x264 bf16 (33792 B) | h1 64x264 bf16 (33792, aliased by s 8x256 f32)
    //      xcat 8x336 bf16 (5376) | w3 3x256 f32 (3072) | rl 8x24 f32 (768) = 76800 B
    __shared__ __attribute__((aligned(16))) unsigned short h0s[64 * 264];
    __shared__ __attribute__((aligned(16))) unsigned short h1s[64 * 264];
    __shared__ __attribute__((aligned(16))) unsigned short xcat[NODES2 * 336];
    __shared__ __attribute__((aligned(16))) float w3buf[3 * 256];
    __shared__ __attribute__((aligned(16))) float rl[NODES2 * 24];
    float* s = (float*)h1s;   // [8][256] pre-activation, dead before h1 written

    const int tid  = threadIdx.x;
    const int lane = tid & 63;
    const int w    = tid >> 6;      // wave id 0..3 -> cols [64w, 64w+64)
    const int quad = lane >> 4;     // 0..3
    const int l15  = lane & 15;
    const int blk  = blockIdx.x;
    const size_t nb = (size_t)blk * NODES2;

    // ---- stage inputs (fp32 -> bf16 for MFMA operands)
    for (int e = tid; e < NODES2 * 256; e += 256) {
        int r = e >> 8, c = e & 255;
        xcat[r * 336 + c] = f2bf(x[(nb + r) * 256 + c]);
    }
    for (int e = tid; e < NODES2 * 64; e += 256) {
        int r = e >> 6, c = e & 63;
        xcat[r * 336 + 256 + c] = f2bf(feats_ws[(nb + r) * 64 + c]);
    }
    for (int e = tid; e < 3 * 256; e += 256) {
        int r = e >> 8, c = e & 255;
        w3buf[e] = W0f[(size_t)(320 + r) * 256 + c];
    }
    if (tid < NODES2 * 24) rl[tid] = rel_in[nb * 24 + tid];
    __syncthreads();

    // ---- layer 0 MFMA: [8(pad16) x 320] @ W0t -> s (pre-relu, pre-rel)
    {
        const unsigned short* W0t = wbf;                    // [256 n][320 k]
        f32x4 acc[4];
        f32x4 z = {0.f, 0.f, 0.f, 0.f};
        #pragma unroll
        for (int t = 0; t < 4; ++t) acc[t] = z;
        const unsigned short* arow = &xcat[(lane & 7) * 336];
        for (int ks = 0; ks < 10; ++ks) {
            int k0 = ks * 32 + quad * 8;
            bf16x8 a = *(const bf16x8*)(arow + k0);
            #pragma unroll
            for (int t = 0; t < 4; ++t) {
                int n = w * 64 + t * 16 + l15;
                bf16x8 b = *(const bf16x8*)(W0t + (size_t)n * 320 + k0);
                acc[t] = __builtin_amdgcn_mfma_f32_16x16x32_bf16(a, b, acc[t], 0, 0, 0);
            }
        }
        #pragma unroll
        for (int t = 0; t < 4; ++t) {
            int col = w * 64 + t * 16 + l15;
            float bb = b0[col];
            #pragma unroll
            for (int r = 0; r < 4; ++r) {
                int row = quad * 4 + r;    // rows 8..15 are duplicates; drop
                if (row < NODES2) s[row * 256 + col] = acc[t][r] + bb;
            }
        }
    }
    __syncthreads();

    // ---- expand s -> h0[64][256] bf16 with rank-3 rel correction + relu
    for (int it = 0; it < 16; ++it) {
        int task = tid + it * 256;          // 64 rows x 64 col-groups
        int row = task >> 6;
        int cg  = task & 63;
        int node = row >> 3, p = row & 7;
        float4 sv = *(const float4*)&s[node * 256 + cg * 4];
        float ra = rl[node * 24 + p * 3 + 0];
        float rb = rl[node * 24 + p * 3 + 1];
        float rc = rl[node * 24 + p * 3 + 2];
        float4 wa = *(const float4*)&w3buf[cg * 4];
        float4 wbv = *(const float4*)&w3buf[256 + cg * 4];
        float4 wc = *(const float4*)&w3buf[512 + cg * 4];
        float v0 = fmaxf(sv.x + ra * wa.x + rb * wbv.x + rc * wc.x, 0.f);
        float v1 = fmaxf(sv.y + ra * wa.y + rb * wbv.y + rc * wc.y, 0.f);
        float v2 = fmaxf(sv.z + ra * wa.z + rb * wbv.z + rc * wc.z, 0.f);
        float v3 = fmaxf(sv.w + ra * wa.w + rb * wbv.w + rc * wc.w, 0.f);
        unsigned int lo = (unsigned int)f2bf(v0) | ((unsigned int)f2bf(v1) << 16);
        unsigned int hi = (unsigned int)f2bf(v2) | ((unsigned int)f2bf(v3) << 16);
        uint2 pk; pk.x = lo; pk.y = hi;
        *(uint2*)&h0s[row * 264 + cg * 4] = pk;
    }
    __syncthreads();

    // ---- FC1: h1 = relu(h0 @ W1 + b1), 64x256 via MFMA
    {
        const unsigned short* W1t = wbf + 81920;            // [256 n][256 k]
        f32x4 acc[4][4];
        f32x4 z = {0.f, 0.f, 0.f, 0.f};
        #pragma unroll
        for (int m = 0; m < 4; ++m)
            #pragma unroll
            for (int t = 0; t < 4; ++t) acc[m][t] = z;
        for (int ks = 0; ks < 8; ++ks) {
            int k0 = ks * 32 + quad * 8;
            bf16x8 a[4], b[4];
            #pragma unroll
            for (int m = 0; m < 4; ++m)
                a[m] = *(const bf16x8*)&h0s[(m * 16 + l15) * 264 + k0];
            #pragma unroll
            for (int t = 0; t < 4; ++t)
                b[t] = *(const bf16x8*)(W1t + (size_t)(w * 64 + t * 16 + l15) * 256 + k0);
            #pragma unroll
            for (int m = 0; m < 4; ++m)
                #pragma unroll
                for (int t = 0; t < 4; ++t)
                    acc[m][t] = __builtin_amdgcn_mfma_f32_16x16x32_bf16(a[m], b[t], acc[m][t], 0, 0, 0);
        }
        #pragma unroll
        for (int t = 0; t < 4; ++t) {
            int col = w * 64 + t * 16 + l15;
            float bb = b1[col];
            #pragma unroll
            for (int m = 0; m < 4; ++m) {
                #pragma unroll
                for (int r = 0; r < 4; ++r) {
                    int row = m * 16 + quad * 4 + r;
                    h1s[row * 264 + col] = f2bf(fmaxf(acc[m][t][r] + bb, 0.f));
                }
            }
        }
    }
    __syncthreads();

    // ---- FC2: out = relu(h1 @ W2 + b2) -> global fp32
    {
        const unsigned short* W2t = wbf + 147456;
        f32x4 acc[4][4];
        f32x4 z = {0.f, 0.f, 0.f, 0.f};
        #pragma unroll
        for (int m = 0; m < 4; ++m)
            #pragma unroll
            for (int t = 0; t < 4; ++t) acc[m][t] = z;
        for (int ks = 0; ks < 8; ++ks) {
            int k0 = ks * 32 + quad * 8;
            bf16x8 a[4], b[4];
            #pragma unroll
            for (int m = 0; m < 4; ++m)
                a[m] = *(const bf16x8*)&h1s[(m * 16 + l15) * 264 + k0];
            #pragma unroll
            for (int t = 0; t < 4; ++t)
                b[t] = *(const bf16x8*)(W2t + (size_t)(w * 64 + t * 16 + l15) * 256 + k0);
            #pragma unroll
            for (int m = 0; m < 4; ++m)
                #pragma unroll
                for (int t = 0; t < 4; ++t)
                    acc[m][t] = __builtin_amdgcn_mfma_f32_16x16x32_bf16(a[m], b[t], acc[m][t], 0, 0, 0);
        }
        #pragma unroll
        for (int t = 0; t < 4; ++t) {
            int col = w * 64 + t * 16 + l15;
            float bb = b2[col];
            #pragma unroll
            for (int m = 0; m < 4; ++m) {
                #pragma unroll
                for (int r = 0; r < 4; ++r) {
                    int row = m * 16 + quad * 4 + r;
                    out_dec[(nb * 8 + row) * 256 + col] = fmaxf(acc[m][t][r] + bb, 0.f);
                }
            }
        }
    }
}

// ---------------------------------------------------------------------------
extern "C" void kernel_launch(void* const* d_in, const int* in_sizes, int n_in,
                              void* d_out, int out_size, void* d_ws, size_t ws_size,
                              hipStream_t stream) {
    const float* x    = (const float*)d_in[0];
    const float* Wg0  = (const float*)d_in[1];
    const float* bg0  = (const float*)d_in[2];
    const float* Wg1  = (const float*)d_in[3];
    const float* bg1  = (const float*)d_in[4];
    const float* Wg2  = (const float*)d_in[5];
    const float* bg2  = (const float*)d_in[6];
    const float* Wdec = (const float*)d_in[7];
    const float* bdec = (const float*)d_in[8];
    const float* W0   = (const float*)d_in[9];
    const float* b0   = (const float*)d_in[10];
    const float* W1   = (const float*)d_in[11];
    const float* b1   = (const float*)d_in[12];
    const float* W2   = (const float*)d_in[13];
    const float* b2   = (const float*)d_in[14];

    float* out      = (float*)d_out;
    float* out_rel  = out;                         // [400000, 3]
    float* out_dec  = out + 1200000;               // [400000, 256]
    float* out_clu  = out + 103600000;             // [400000] as float

    unsigned short* wbf = (unsigned short*)d_ws;
    float* feats_ws = (float*)((char*)d_ws + 425984);   // [50000, 64]

    k_prep<<<832, 256, 0, stream>>>(W0, W1, W2, wbf);
    k_global<<<NN / TM1, 256, 0, stream>>>(x, Wg0, bg0, Wg1, bg1, Wg2, bg2,
                                           Wdec, bdec, feats_ws, out_rel, out_clu);
    k_points<<<NN / NODES2, 256, 0, stream>>>(x, feats_ws, out_rel,
                                              wbf, W0, b0, b1, b2, out_dec);
}